// Round 4
// baseline (3508.279 us; speedup 1.0000x reference)
//
#include <hip/hip_runtime.h>
#include <hip/hip_bf16.h>
#include <math.h>

#define ND 100000
#define NS 50000
#define NE1 500000
#define NE2 250000
#define DIM 128
#define NH 4
#define HDI 32

typedef __hip_bfloat16 bf16;

__device__ __forceinline__ float ldf(const float* p, size_t i) { return p[i]; }
__device__ __forceinline__ float ldf(const bf16* p, size_t i) { return __bfloat162float(p[i]); }
__device__ __forceinline__ void stf(float* p, size_t i, float v) { p[i] = v; }
__device__ __forceinline__ void stf(bf16* p, size_t i, float v) { p[i] = __float2bfloat16(v); }

// ---------- diagnostics ----------
__global__ void fill16_kernel(unsigned short* p, unsigned short v, size_t n) {
    size_t i = (size_t)blockIdx.x * blockDim.x + threadIdx.x;
    if (i < n) p[i] = v;
}

// flag=1 if float inputs are fp32, flag=0 if bf16.
// Little-endian fp32: ushort[2k] = LOW mantissa half (random bits -> wild
// exponents when viewed as bf16); ushort[2k+1] = sign/exponent half.
// Real bf16 weights (~N(0,0.05^2)) never have exponent >= 0x90 (|v|>=2^17).
// So: sample EVEN ushort indices; any exponent >= 0x90 => fp32.
__global__ __launch_bounds__(64) void detect_kernel(const unsigned short* w, int* flag) {
    int lane = threadIdx.x;
    int mx = 0;
    for (int j = 0; j < 32; ++j) {
        int i = 2 * (lane + 64 * j);   // even ushort indices, < 4096 (8 KB: in-bounds either dtype)
        int e = (w[i] >> 7) & 0xFF;
        mx = mx > e ? mx : e;
    }
    for (int d = 32; d; d >>= 1) { int o = __shfl_xor(mx, d); mx = mx > o ? mx : o; }
    if (lane == 0) flag[0] = (mx >= 0x90) ? 1 : 0;
}

// ---------- node projections ----------
template <typename T>
__device__ __forceinline__ void proj2_body(
    const T* X, const T* W1, const T* b1, const T* W2, const T* b2,
    bf16* Y1, bf16* Y2)
{
    __shared__ float xs[DIM];
    int n = blockIdx.x, d = threadIdx.x;
    xs[d] = ldf(X, (size_t)n * DIM + d);
    __syncthreads();
    float a1 = ldf(b1, d), a2 = ldf(b2, d);
#pragma unroll 4
    for (int k = 0; k < DIM; ++k) {
        float xv = xs[k];
        a1 = fmaf(xv, ldf(W1, k * DIM + d), a1);
        a2 = fmaf(xv, ldf(W2, k * DIM + d), a2);
    }
    Y1[(size_t)n * DIM + d] = __float2bfloat16(a1);
    Y2[(size_t)n * DIM + d] = __float2bfloat16(a2);
}

__global__ __launch_bounds__(128) void proj2_kernel(
    const int* __restrict__ flag, const void* X,
    const void* W1, const void* b1, const void* W2, const void* b2,
    bf16* __restrict__ Y1, bf16* __restrict__ Y2)
{
    if (flag[0]) proj2_body((const float*)X, (const float*)W1, (const float*)b1,
                            (const float*)W2, (const float*)b2, Y1, Y2);
    else         proj2_body((const bf16*)X, (const bf16*)W1, (const bf16*)b1,
                            (const bf16*)W2, (const bf16*)b2, Y1, Y2);
}

template <typename T>
__device__ __forceinline__ void proj1_body(const T* X, const T* W, const T* b, bf16* Y)
{
    __shared__ float xs[DIM];
    int n = blockIdx.x, d = threadIdx.x;
    xs[d] = ldf(X, (size_t)n * DIM + d);
    __syncthreads();
    float a = ldf(b, d);
#pragma unroll 4
    for (int k = 0; k < DIM; ++k)
        a = fmaf(xs[k], ldf(W, k * DIM + d), a);
    Y[(size_t)n * DIM + d] = __float2bfloat16(a);
}

__global__ __launch_bounds__(128) void proj1_kernel(
    const int* __restrict__ flag, const void* X, const void* W, const void* b,
    bf16* __restrict__ Y)
{
    if (flag[0]) proj1_body((const float*)X, (const float*)W, (const float*)b, Y);
    else         proj1_body((const bf16*)X, (const bf16*)W, (const bf16*)b, Y);
}

// out[n] = ( (A[n] / s[n,head]) @ W + b )  -- folds softmax denominator; out dtype = T
template <typename T>
__device__ __forceinline__ void projout_body(
    const float* A, const float* s, const T* W, const T* b, void* out, size_t off)
{
    __shared__ float xs[DIM];
    int n = blockIdx.x, d = threadIdx.x;
    xs[d] = A[(size_t)n * DIM + d] / (s[(size_t)n * NH + (d >> 5)] + 1e-16f);
    __syncthreads();
    float a = ldf(b, d);
#pragma unroll 4
    for (int k = 0; k < DIM; ++k)
        a = fmaf(xs[k], ldf(W, k * DIM + d), a);
    stf((T*)out + off, (size_t)n * DIM + d, a);
}

__global__ __launch_bounds__(128) void projout_kernel(
    const int* __restrict__ flag, const float* __restrict__ A, const float* __restrict__ s,
    const void* W, const void* b, void* out, size_t off)
{
    if (flag[0]) projout_body(A, s, (const float*)W, (const float*)b, out, off);
    else         projout_body(A, s, (const bf16*)W, (const bf16*)b, out, off);
}

// ---------- edge kernel ----------
// One wave per edge; lane owns dims d0=2*lane, d0+1 (head = lane>>4).
// aggr[di] += exp(logit_h) * mh ; s[di,h] += exp(logit_h). Normalization deferred
// to projout (softmax denominator is constant per segment).
template <bool GATED, typename T>
__device__ __forceinline__ void edge_body(
    const bf16* Xs, const bf16* Xd,
    const int* src, const int* dst, const int* cat,
    const T* econt, const T* emb,
    const T* gW1, const T* gb1, const T* gW2, const T* gb2,
    const T* attn, float* s_out, float* aggr)
{
    int e = blockIdx.x;
    int lane = threadIdx.x;
    int si = src[e], di = dst[e];
    int d0 = lane * 2;

    float gate0 = 1.0f, gate1 = 1.0f;
    if constexpr (GATED) {
        __shared__ float gf[36];
        __shared__ float h1[DIM];
        int c = cat[e];
        if (lane < 32) gf[lane] = ldf(emb, c * 32 + lane);
        else if (lane < 36) gf[lane] = ldf(econt, (size_t)e * 4 + (lane - 32));
        __syncthreads();
        {
            int j0 = lane, j1 = lane + 64;
            float a0 = ldf(gb1, j0), a1 = ldf(gb1, j1);
#pragma unroll 4
            for (int k = 0; k < 36; ++k) {
                float g = gf[k];
                a0 = fmaf(g, ldf(gW1, k * DIM + j0), a0);
                a1 = fmaf(g, ldf(gW1, k * DIM + j1), a1);
            }
            // exact gelu: x * 0.5 * (1 + erf(x/sqrt(2)))
            h1[j0] = 0.5f * a0 * (1.0f + erff(a0 * 0.70710678118654752440f));
            h1[j1] = 0.5f * a1 * (1.0f + erff(a1 * 0.70710678118654752440f));
        }
        __syncthreads();
        {
            float a0 = ldf(gb2, d0), a1 = ldf(gb2, d0 + 1);
#pragma unroll 4
            for (int j = 0; j < DIM; ++j) {
                float hv = h1[j];
                a0 = fmaf(hv, ldf(gW2, j * DIM + d0), a0);
                a1 = fmaf(hv, ldf(gW2, j * DIM + d0 + 1), a1);
            }
            gate0 = 1.0f / (1.0f + expf(-a0));
            gate1 = 1.0f / (1.0f + expf(-a1));
        }
    }

    float sx = __bfloat162float(Xs[(size_t)si * DIM + d0]);
    float sy = __bfloat162float(Xs[(size_t)si * DIM + d0 + 1]);
    float dx = __bfloat162float(Xd[(size_t)di * DIM + d0]);
    float dy = __bfloat162float(Xd[(size_t)di * DIM + d0 + 1]);
    float m0 = (sx + dx) * gate0;
    float m1 = (sy + dy) * gate1;

    // logit: (sh*dh).sum / sqrt(32) + (mh*attn).sum per head
    int h = lane >> 4;
    int k0 = d0 & 31;
    const float rs = 0.17677669529663688110f;  // 1/sqrt(32)
    float p = (sx * dx + sy * dy) * rs
            + m0 * ldf(attn, h * HDI + k0) + m1 * ldf(attn, h * HDI + k0 + 1);
    p += __shfl_xor(p, 8);
    p += __shfl_xor(p, 4);
    p += __shfl_xor(p, 2);
    p += __shfl_xor(p, 1);
    p = fminf(p, 80.0f);             // defensive: keep exp finite
    float ev = expf(p);              // logits are O(1): no max subtraction needed

    if ((lane & 15) == 0)
        atomicAdd(&s_out[(size_t)di * NH + h], ev);
    float* ap = &aggr[(size_t)di * DIM + d0];
    atomicAdd(ap, ev * m0);
    atomicAdd(ap + 1, ev * m1);
}

template <bool GATED>
__global__ __launch_bounds__(64) void edge_kernel(
    const int* __restrict__ flag,
    const bf16* __restrict__ Xs, const bf16* __restrict__ Xd,
    const int* __restrict__ src, const int* __restrict__ dst,
    const int* __restrict__ cat, const void* econt, const void* emb,
    const void* gW1, const void* gb1, const void* gW2, const void* gb2,
    const void* attn, float* __restrict__ s_out, float* __restrict__ aggr)
{
    if (flag[0])
        edge_body<GATED>(Xs, Xd, src, dst, cat,
                         (const float*)econt, (const float*)emb,
                         (const float*)gW1, (const float*)gb1,
                         (const float*)gW2, (const float*)gb2,
                         (const float*)attn, s_out, aggr);
    else
        edge_body<GATED>(Xs, Xd, src, dst, cat,
                         (const bf16*)econt, (const bf16*)emb,
                         (const bf16*)gW1, (const bf16*)gb1,
                         (const bf16*)gW2, (const bf16*)gb2,
                         (const bf16*)attn, s_out, aggr);
}

extern "C" void kernel_launch(void* const* d_in, const int* in_sizes, int n_in,
                              void* d_out, int out_size, void* d_ws, size_t ws_size,
                              hipStream_t stream)
{
    const void* x_drug  = d_in[0];
    const void* x_dis   = d_in[1];
    const void* e1_cont = d_in[2];
    const void* W_src1  = d_in[3];
    const void* b_src1  = d_in[4];
    const void* W_dst1  = d_in[5];
    const void* b_dst1  = d_in[6];
    const void* attn1   = d_in[7];
    const void* emb1    = d_in[8];
    const void* gW1     = d_in[9];
    const void* gb1     = d_in[10];
    const void* gW2     = d_in[11];
    const void* gb2     = d_in[12];
    const void* W_src2  = d_in[13];
    const void* b_src2  = d_in[14];
    const void* W_dst2  = d_in[15];
    const void* b_dst2  = d_in[16];
    const void* attn2   = d_in[17];
    const void* Wo_drug = d_in[18];
    const void* bo_drug = d_in[19];
    const void* Wo_dis  = d_in[20];
    const void* bo_dis  = d_in[21];
    const int* e1_src = (const int*)d_in[22];
    const int* e1_dst = (const int*)d_in[23];
    const int* e2_src = (const int*)d_in[24];
    const int* e2_dst = (const int*)d_in[25];
    const int* e1_cat = (const int*)d_in[26];

    // ---- diagnostic guard 1: input order/sizes (signature 77.0 if wrong) ----
    bool sizes_ok = (n_in == 27)
        && in_sizes[0] == ND * DIM && in_sizes[1] == NS * DIM
        && in_sizes[2] == NE1 * 4
        && in_sizes[3] == DIM * DIM && in_sizes[4] == DIM
        && in_sizes[5] == DIM * DIM && in_sizes[6] == DIM
        && in_sizes[7] == NH * HDI && in_sizes[8] == 8 * 32
        && in_sizes[9] == 36 * DIM && in_sizes[10] == DIM
        && in_sizes[11] == DIM * DIM && in_sizes[12] == DIM
        && in_sizes[13] == DIM * DIM && in_sizes[17] == NH * HDI
        && in_sizes[18] == DIM * DIM && in_sizes[20] == DIM * DIM
        && in_sizes[22] == NE1 && in_sizes[23] == NE1
        && in_sizes[24] == NE2 && in_sizes[25] == NE2 && in_sizes[26] == NE1;
    if (!sizes_ok) {
        size_t n = (size_t)out_size;
        fill16_kernel<<<(int)((n + 255) / 256), 256, 0, stream>>>((unsigned short*)d_out, 0x429A, n);
        return;
    }

    // ---- workspace layout: [flag 64B][Xs 25.6M][Xd 25.6M][sb 1.6M][aggr 51.2M] ----
    size_t off_flag = 0;
    size_t off_Xs   = 64;
    size_t off_Xd   = off_Xs + (size_t)ND * DIM * 2;
    size_t off_sb   = off_Xd + (size_t)ND * DIM * 2;
    size_t off_aggr = off_sb + (size_t)ND * NH * 4;
    size_t need     = off_aggr + (size_t)ND * DIM * 4;

    // ---- diagnostic guard 2: workspace size (signature 123.0 if too small) ----
    if (ws_size < need) {
        size_t n = (size_t)out_size;
        fill16_kernel<<<(int)((n + 255) / 256), 256, 0, stream>>>((unsigned short*)d_out, 0x42F6, n);
        return;
    }

    char* w = (char*)d_ws;
    int*   flag = (int*)(w + off_flag);
    bf16*  Xs   = (bf16*)(w + off_Xs);
    bf16*  Xd   = (bf16*)(w + off_Xd);
    float* sb   = (float*)(w + off_sb);
    float* aggr = (float*)(w + off_aggr);

    // ---- dtype detection (writes flag; fixed endianness: sample EVEN ushorts) ----
    detect_kernel<<<1, 64, 0, stream>>>((const unsigned short*)W_src1, flag);

    // ---- phase 1: drug -> drug (gated) ----
    hipMemsetAsync(sb, 0, (size_t)ND * NH * 4, stream);
    hipMemsetAsync(aggr, 0, (size_t)ND * DIM * 4, stream);
    proj2_kernel<<<ND, 128, 0, stream>>>(flag, x_drug, W_src1, b_src1, W_dst1, b_dst1, Xs, Xd);
    edge_kernel<true><<<NE1, 64, 0, stream>>>(
        flag, Xs, Xd, e1_src, e1_dst, e1_cat, e1_cont, emb1,
        gW1, gb1, gW2, gb2, attn1, sb, aggr);
    projout_kernel<<<ND, 128, 0, stream>>>(flag, aggr, sb, Wo_drug, bo_drug, d_out, 0);

    // ---- phase 2: drug -> disease (no gate) ----
    hipMemsetAsync(sb, 0, (size_t)NS * NH * 4, stream);
    hipMemsetAsync(aggr, 0, (size_t)NS * DIM * 4, stream);
    proj1_kernel<<<ND, 128, 0, stream>>>(flag, x_drug, W_src2, b_src2, Xs);
    proj1_kernel<<<NS, 128, 0, stream>>>(flag, x_dis, W_dst2, b_dst2, Xd);
    edge_kernel<false><<<NE2, 64, 0, stream>>>(
        flag, Xs, Xd, e2_src, e2_dst, (const int*)nullptr, nullptr, nullptr,
        nullptr, nullptr, nullptr, nullptr, attn2, sb, aggr);
    projout_kernel<<<NS, 128, 0, stream>>>(flag, aggr, sb, Wo_dis, bo_dis, d_out, (size_t)ND * DIM);
}

// Round 5
// 2538.692 us; speedup vs baseline: 1.3819x; 1.3819x over previous
//
#include <hip/hip_runtime.h>
#include <hip/hip_bf16.h>
#include <math.h>

#define ND 100000
#define NS 50000
#define NE1 500000
#define NE2 250000
#define DIM 128
#define NH 4
#define HDI 32
#define GRID_P 768   // 3 blocks/CU * 256 CUs

typedef __hip_bfloat16 bf16;
typedef unsigned short u16;
typedef unsigned int u32;

__device__ __forceinline__ float ldf(const float* p, size_t i) { return p[i]; }
__device__ __forceinline__ float ldf(const bf16* p, size_t i) { return __bfloat162float(p[i]); }
__device__ __forceinline__ void stf(float* p, size_t i, float v) { p[i] = v; }
__device__ __forceinline__ void stf(bf16* p, size_t i, float v) { p[i] = __float2bfloat16(v); }
__device__ __forceinline__ float b2f(bf16 v) { return __bfloat162float(v); }

__device__ __forceinline__ u16 f2bfu(float f) {
    __hip_bfloat16 h = __float2bfloat16(f);
    union { __hip_bfloat16 b; u16 u; } c; c.b = h; return c.u;
}
// unpack a bf16 pair (packed in one dword, little-endian) to two floats
__device__ __forceinline__ float2 bfp(u32 u) {
    float2 r;
    r.x = __uint_as_float(u << 16);
    r.y = __uint_as_float(u & 0xffff0000u);
    return r;
}
// uniform-lane broadcast (compile-time lane after unroll -> v_readlane)
__device__ __forceinline__ float rlf(float v, int l) {
    return __uint_as_float(__builtin_amdgcn_readlane(__float_as_uint(v), l));
}

// ---------- diagnostics ----------
__global__ void fill16_kernel(u16* p, u16 v, size_t n) {
    size_t i = (size_t)blockIdx.x * blockDim.x + threadIdx.x;
    if (i < n) p[i] = v;
}

// flag=1 if float inputs are fp32, flag=0 if bf16 (sample EVEN ushorts = fp32
// low-mantissa halves; real bf16 weights never have exponent >= 0x90).
__global__ __launch_bounds__(64) void detect_kernel(const u16* w, int* flag) {
    int lane = threadIdx.x;
    int mx = 0;
    for (int j = 0; j < 32; ++j) {
        int i = 2 * (lane + 64 * j);
        int e = (w[i] >> 7) & 0xFF;
        mx = mx > e ? mx : e;
    }
    for (int d = 32; d; d >>= 1) { int o = __shfl_xor(mx, d); mx = mx > o ? mx : o; }
    if (lane == 0) flag[0] = (mx >= 0x90) ? 1 : 0;
}

// ---------- node projections: wave-per-node, LDS-staged bf16 weights ----------
template <typename T>
__device__ __forceinline__ void proj2_body(
    u16* W1s, u16* W2s,
    const T* X, const T* W1, const T* b1, const T* W2, const T* b2,
    bf16* Y1, bf16* Y2, int N)
{
    int tid = threadIdx.x;
    for (int i = tid; i < DIM * DIM; i += 256) {
        W1s[i] = f2bfu(ldf(W1, i));
        W2s[i] = f2bfu(ldf(W2, i));
    }
    __syncthreads();
    const u32* W1u = (const u32*)W1s;
    const u32* W2u = (const u32*)W2s;
    int lane = tid & 63, d0 = 2 * lane;
    float b10 = ldf(b1, d0), b11 = ldf(b1, d0 + 1);
    float b20 = ldf(b2, d0), b21 = ldf(b2, d0 + 1);
    int wid = blockIdx.x * 4 + (tid >> 6);
    for (int n = wid; n < N; n += GRID_P * 4) {
        float xA = ldf(X, (size_t)n * DIM + d0);
        float xB = ldf(X, (size_t)n * DIM + d0 + 1);
        float a0 = b10, a1 = b11, c0 = b20, c1 = b21;
#pragma unroll
        for (int k = 0; k < DIM; k += 2) {
            float x0 = rlf(xA, k >> 1), x1 = rlf(xB, k >> 1);
            float2 wa = bfp(W1u[k * 64 + lane]);
            float2 wb = bfp(W1u[(k + 1) * 64 + lane]);
            a0 = fmaf(x0, wa.x, a0); a1 = fmaf(x0, wa.y, a1);
            a0 = fmaf(x1, wb.x, a0); a1 = fmaf(x1, wb.y, a1);
            float2 wc = bfp(W2u[k * 64 + lane]);
            float2 wd = bfp(W2u[(k + 1) * 64 + lane]);
            c0 = fmaf(x0, wc.x, c0); c1 = fmaf(x0, wc.y, c1);
            c0 = fmaf(x1, wd.x, c0); c1 = fmaf(x1, wd.y, c1);
        }
        Y1[(size_t)n * DIM + d0]     = __float2bfloat16(a0);
        Y1[(size_t)n * DIM + d0 + 1] = __float2bfloat16(a1);
        Y2[(size_t)n * DIM + d0]     = __float2bfloat16(c0);
        Y2[(size_t)n * DIM + d0 + 1] = __float2bfloat16(c1);
    }
}

__global__ __launch_bounds__(256) void proj2_kernel(
    const int* __restrict__ flag, const void* X,
    const void* W1, const void* b1, const void* W2, const void* b2,
    bf16* __restrict__ Y1, bf16* __restrict__ Y2, int N)
{
    __shared__ u16 W1s[DIM * DIM];
    __shared__ u16 W2s[DIM * DIM];
    if (flag[0]) proj2_body(W1s, W2s, (const float*)X, (const float*)W1, (const float*)b1,
                            (const float*)W2, (const float*)b2, Y1, Y2, N);
    else         proj2_body(W1s, W2s, (const bf16*)X, (const bf16*)W1, (const bf16*)b1,
                            (const bf16*)W2, (const bf16*)b2, Y1, Y2, N);
}

template <typename T>
__device__ __forceinline__ void proj1_body(
    u16* W1s, const T* X, const T* W, const T* b, bf16* Y, int N)
{
    int tid = threadIdx.x;
    for (int i = tid; i < DIM * DIM; i += 256) W1s[i] = f2bfu(ldf(W, i));
    __syncthreads();
    const u32* Wu = (const u32*)W1s;
    int lane = tid & 63, d0 = 2 * lane;
    float b10 = ldf(b, d0), b11 = ldf(b, d0 + 1);
    int wid = blockIdx.x * 4 + (tid >> 6);
    for (int n = wid; n < N; n += GRID_P * 4) {
        float xA = ldf(X, (size_t)n * DIM + d0);
        float xB = ldf(X, (size_t)n * DIM + d0 + 1);
        float a0 = b10, a1 = b11;
#pragma unroll
        for (int k = 0; k < DIM; k += 2) {
            float x0 = rlf(xA, k >> 1), x1 = rlf(xB, k >> 1);
            float2 wa = bfp(Wu[k * 64 + lane]);
            float2 wb = bfp(Wu[(k + 1) * 64 + lane]);
            a0 = fmaf(x0, wa.x, a0); a1 = fmaf(x0, wa.y, a1);
            a0 = fmaf(x1, wb.x, a0); a1 = fmaf(x1, wb.y, a1);
        }
        Y[(size_t)n * DIM + d0]     = __float2bfloat16(a0);
        Y[(size_t)n * DIM + d0 + 1] = __float2bfloat16(a1);
    }
}

__global__ __launch_bounds__(256) void proj1_kernel(
    const int* __restrict__ flag, const void* X, const void* W, const void* b,
    bf16* __restrict__ Y, int N)
{
    __shared__ u16 W1s[DIM * DIM];
    if (flag[0]) proj1_body(W1s, (const float*)X, (const float*)W, (const float*)b, Y, N);
    else         proj1_body(W1s, (const bf16*)X, (const bf16*)W, (const bf16*)b, Y, N);
}

// out[n] = (A[n] / s[n,head]) @ W + b   (softmax denominator folded in)
template <typename T>
__device__ __forceinline__ void projout_body(
    u16* W1s, const float* A, const float* s, const T* W, const T* b,
    void* out, size_t off, int N)
{
    int tid = threadIdx.x;
    for (int i = tid; i < DIM * DIM; i += 256) W1s[i] = f2bfu(ldf(W, i));
    __syncthreads();
    const u32* Wu = (const u32*)W1s;
    int lane = tid & 63, d0 = 2 * lane, h = lane >> 4;
    float b10 = ldf(b, d0), b11 = ldf(b, d0 + 1);
    int wid = blockIdx.x * 4 + (tid >> 6);
    for (int n = wid; n < N; n += GRID_P * 4) {
        float inv = 1.0f / (s[(size_t)n * NH + h] + 1e-16f);
        float xA = A[(size_t)n * DIM + d0] * inv;
        float xB = A[(size_t)n * DIM + d0 + 1] * inv;
        float a0 = b10, a1 = b11;
#pragma unroll
        for (int k = 0; k < DIM; k += 2) {
            float x0 = rlf(xA, k >> 1), x1 = rlf(xB, k >> 1);
            float2 wa = bfp(Wu[k * 64 + lane]);
            float2 wb = bfp(Wu[(k + 1) * 64 + lane]);
            a0 = fmaf(x0, wa.x, a0); a1 = fmaf(x0, wa.y, a1);
            a0 = fmaf(x1, wb.x, a0); a1 = fmaf(x1, wb.y, a1);
        }
        stf((T*)out + off, (size_t)n * DIM + d0, a0);
        stf((T*)out + off, (size_t)n * DIM + d0 + 1, a1);
    }
}

__global__ __launch_bounds__(256) void projout_kernel(
    const int* __restrict__ flag, const float* __restrict__ A, const float* __restrict__ s,
    const void* W, const void* b, void* out, size_t off, int N)
{
    __shared__ u16 W1s[DIM * DIM];
    if (flag[0]) projout_body(W1s, A, s, (const float*)W, (const float*)b, out, off, N);
    else         projout_body(W1s, A, s, (const bf16*)W, (const bf16*)b, out, off, N);
}

// ---------- gated edge kernel: LDS-staged bf16 gate weights, wave-per-edge ----------
template <typename T>
__device__ __forceinline__ void edge1_body(
    u16* W1s, u16* W2s,
    const bf16* Xs, const bf16* Xd,
    const int* src, const int* dst, const int* cat,
    const T* econt, const T* emb,
    const T* gW1, const T* gb1, const T* gW2, const T* gb2,
    const T* attn, float* s_out, float* aggr)
{
    int tid = threadIdx.x;
    for (int i = tid; i < 36 * DIM; i += 256) W1s[i] = f2bfu(ldf(gW1, i));
    for (int i = tid; i < DIM * DIM; i += 256) W2s[i] = f2bfu(ldf(gW2, i));
    __syncthreads();
    const u32* W1u = (const u32*)W1s;
    const u32* W2u = (const u32*)W2s;

    int lane = tid & 63, d0 = 2 * lane;
    int h = lane >> 4, k0 = d0 & 31;
    // loop-invariant per-lane params
    float b10 = ldf(gb1, d0), b11 = ldf(gb1, d0 + 1);
    float b20 = ldf(gb2, d0), b21 = ldf(gb2, d0 + 1);
    float av0 = ldf(attn, h * HDI + k0), av1 = ldf(attn, h * HDI + k0 + 1);
    const float rs = 0.17677669529663688110f;  // 1/sqrt(32)

    int wid = blockIdx.x * 4 + (tid >> 6);
    for (int e = wid; e < NE1; e += GRID_P * 4) {
        int si = src[e], di = dst[e], c = cat[e];
        // gate features distributed one per lane (lanes 36..63 hold 0)
        float gfv = 0.0f;
        if (lane < 32) gfv = ldf(emb, c * 32 + lane);
        else if (lane < 36) gfv = ldf(econt, (size_t)e * 4 + (lane - 32));

        // GEMM1 [36] -> [128]; lane owns outputs d0, d0+1
        float a0 = b10, a1 = b11;
#pragma unroll
        for (int k = 0; k < 36; ++k) {
            float sc = rlf(gfv, k);
            float2 wv = bfp(W1u[k * 64 + lane]);
            a0 = fmaf(sc, wv.x, a0);
            a1 = fmaf(sc, wv.y, a1);
        }
        // exact gelu
        float hA = 0.5f * a0 * (1.0f + erff(a0 * 0.70710678118654752440f));
        float hB = 0.5f * a1 * (1.0f + erff(a1 * 0.70710678118654752440f));

        // GEMM2 [128] -> [128]; h1[j]: even j in hA of lane j/2, odd j in hB
        float c0 = b20, c1 = b21;
#pragma unroll
        for (int j = 0; j < DIM; j += 2) {
            float h0 = rlf(hA, j >> 1);
            float h1v = rlf(hB, j >> 1);
            float2 w0 = bfp(W2u[j * 64 + lane]);
            float2 w1 = bfp(W2u[(j + 1) * 64 + lane]);
            c0 = fmaf(h0, w0.x, c0); c1 = fmaf(h0, w0.y, c1);
            c0 = fmaf(h1v, w1.x, c0); c1 = fmaf(h1v, w1.y, c1);
        }
        float gate0 = 1.0f / (1.0f + expf(-c0));
        float gate1 = 1.0f / (1.0f + expf(-c1));

        // epilogue: message, logit, exp, atomics
        __hip_bfloat162 svv = *(const __hip_bfloat162*)&Xs[(size_t)si * DIM + d0];
        __hip_bfloat162 dvv = *(const __hip_bfloat162*)&Xd[(size_t)di * DIM + d0];
        float sx = b2f(svv.x), sy = b2f(svv.y);
        float dx = b2f(dvv.x), dy = b2f(dvv.y);
        float m0 = (sx + dx) * gate0;
        float m1 = (sy + dy) * gate1;

        float p = (sx * dx + sy * dy) * rs + m0 * av0 + m1 * av1;
        p += __shfl_xor(p, 8);
        p += __shfl_xor(p, 4);
        p += __shfl_xor(p, 2);
        p += __shfl_xor(p, 1);
        p = fminf(p, 80.0f);
        float ev = expf(p);

        if ((lane & 15) == 0)
            atomicAdd(&s_out[(size_t)di * NH + h], ev);
        float* ap = &aggr[(size_t)di * DIM + d0];
        atomicAdd(ap, ev * m0);
        atomicAdd(ap + 1, ev * m1);
    }
}

__global__ __launch_bounds__(256) void edge1_kernel(
    const int* __restrict__ flag,
    const bf16* __restrict__ Xs, const bf16* __restrict__ Xd,
    const int* __restrict__ src, const int* __restrict__ dst,
    const int* __restrict__ cat, const void* econt, const void* emb,
    const void* gW1, const void* gb1, const void* gW2, const void* gb2,
    const void* attn, float* __restrict__ s_out, float* __restrict__ aggr)
{
    __shared__ u16 W1s[36 * DIM];
    __shared__ u16 W2s[DIM * DIM];
    if (flag[0])
        edge1_body(W1s, W2s, Xs, Xd, src, dst, cat,
                   (const float*)econt, (const float*)emb,
                   (const float*)gW1, (const float*)gb1,
                   (const float*)gW2, (const float*)gb2,
                   (const float*)attn, s_out, aggr);
    else
        edge1_body(W1s, W2s, Xs, Xd, src, dst, cat,
                   (const bf16*)econt, (const bf16*)emb,
                   (const bf16*)gW1, (const bf16*)gb1,
                   (const bf16*)gW2, (const bf16*)gb2,
                   (const bf16*)attn, s_out, aggr);
}

// ---------- ungated edge kernel (no weights): one wave per edge ----------
template <typename T>
__device__ __forceinline__ void edge2_body(
    const bf16* Xs, const bf16* Xd,
    const int* src, const int* dst,
    const T* attn, float* s_out, float* aggr)
{
    int e = blockIdx.x;
    int lane = threadIdx.x;
    int si = src[e], di = dst[e];
    int d0 = lane * 2;
    int h = lane >> 4, k0 = d0 & 31;
    const float rs = 0.17677669529663688110f;

    __hip_bfloat162 svv = *(const __hip_bfloat162*)&Xs[(size_t)si * DIM + d0];
    __hip_bfloat162 dvv = *(const __hip_bfloat162*)&Xd[(size_t)di * DIM + d0];
    float sx = b2f(svv.x), sy = b2f(svv.y);
    float dx = b2f(dvv.x), dy = b2f(dvv.y);
    float m0 = sx + dx;
    float m1 = sy + dy;

    float p = (sx * dx + sy * dy) * rs
            + m0 * ldf(attn, h * HDI + k0) + m1 * ldf(attn, h * HDI + k0 + 1);
    p += __shfl_xor(p, 8);
    p += __shfl_xor(p, 4);
    p += __shfl_xor(p, 2);
    p += __shfl_xor(p, 1);
    p = fminf(p, 80.0f);
    float ev = expf(p);

    if ((lane & 15) == 0)
        atomicAdd(&s_out[(size_t)di * NH + h], ev);
    float* ap = &aggr[(size_t)di * DIM + d0];
    atomicAdd(ap, ev * m0);
    atomicAdd(ap + 1, ev * m1);
}

__global__ __launch_bounds__(64) void edge2_kernel(
    const int* __restrict__ flag,
    const bf16* __restrict__ Xs, const bf16* __restrict__ Xd,
    const int* __restrict__ src, const int* __restrict__ dst,
    const void* attn, float* __restrict__ s_out, float* __restrict__ aggr)
{
    if (flag[0]) edge2_body(Xs, Xd, src, dst, (const float*)attn, s_out, aggr);
    else         edge2_body(Xs, Xd, src, dst, (const bf16*)attn, s_out, aggr);
}

extern "C" void kernel_launch(void* const* d_in, const int* in_sizes, int n_in,
                              void* d_out, int out_size, void* d_ws, size_t ws_size,
                              hipStream_t stream)
{
    const void* x_drug  = d_in[0];
    const void* x_dis   = d_in[1];
    const void* e1_cont = d_in[2];
    const void* W_src1  = d_in[3];
    const void* b_src1  = d_in[4];
    const void* W_dst1  = d_in[5];
    const void* b_dst1  = d_in[6];
    const void* attn1   = d_in[7];
    const void* emb1    = d_in[8];
    const void* gW1     = d_in[9];
    const void* gb1     = d_in[10];
    const void* gW2     = d_in[11];
    const void* gb2     = d_in[12];
    const void* W_src2  = d_in[13];
    const void* b_src2  = d_in[14];
    const void* W_dst2  = d_in[15];
    const void* b_dst2  = d_in[16];
    const void* attn2   = d_in[17];
    const void* Wo_drug = d_in[18];
    const void* bo_drug = d_in[19];
    const void* Wo_dis  = d_in[20];
    const void* bo_dis  = d_in[21];
    const int* e1_src = (const int*)d_in[22];
    const int* e1_dst = (const int*)d_in[23];
    const int* e2_src = (const int*)d_in[24];
    const int* e2_dst = (const int*)d_in[25];
    const int* e1_cat = (const int*)d_in[26];

    // guard 1: input order/sizes (signature 77.0 if wrong)
    bool sizes_ok = (n_in == 27)
        && in_sizes[0] == ND * DIM && in_sizes[1] == NS * DIM
        && in_sizes[2] == NE1 * 4
        && in_sizes[3] == DIM * DIM && in_sizes[4] == DIM
        && in_sizes[5] == DIM * DIM && in_sizes[6] == DIM
        && in_sizes[7] == NH * HDI && in_sizes[8] == 8 * 32
        && in_sizes[9] == 36 * DIM && in_sizes[10] == DIM
        && in_sizes[11] == DIM * DIM && in_sizes[12] == DIM
        && in_sizes[13] == DIM * DIM && in_sizes[17] == NH * HDI
        && in_sizes[18] == DIM * DIM && in_sizes[20] == DIM * DIM
        && in_sizes[22] == NE1 && in_sizes[23] == NE1
        && in_sizes[24] == NE2 && in_sizes[25] == NE2 && in_sizes[26] == NE1;
    if (!sizes_ok) {
        size_t n = (size_t)out_size;
        fill16_kernel<<<(int)((n + 255) / 256), 256, 0, stream>>>((u16*)d_out, 0x429A, n);
        return;
    }

    // workspace layout: [flag 64B][Xs 25.6M][Xd 25.6M][sb 1.6M][aggr 51.2M]
    size_t off_Xs   = 64;
    size_t off_Xd   = off_Xs + (size_t)ND * DIM * 2;
    size_t off_sb   = off_Xd + (size_t)ND * DIM * 2;
    size_t off_aggr = off_sb + (size_t)ND * NH * 4;
    size_t need     = off_aggr + (size_t)ND * DIM * 4;
    if (ws_size < need) {
        size_t n = (size_t)out_size;
        fill16_kernel<<<(int)((n + 255) / 256), 256, 0, stream>>>((u16*)d_out, 0x42F6, n);
        return;
    }

    char* w = (char*)d_ws;
    int*   flag = (int*)w;
    bf16*  Xs   = (bf16*)(w + off_Xs);
    bf16*  Xd   = (bf16*)(w + off_Xd);
    float* sb   = (float*)(w + off_sb);
    float* aggr = (float*)(w + off_aggr);

    detect_kernel<<<1, 64, 0, stream>>>((const u16*)W_src1, flag);

    // ---- phase 1: drug -> drug (gated) ----
    hipMemsetAsync(sb, 0, (size_t)ND * NH * 4, stream);
    hipMemsetAsync(aggr, 0, (size_t)ND * DIM * 4, stream);
    proj2_kernel<<<GRID_P, 256, 0, stream>>>(flag, x_drug, W_src1, b_src1, W_dst1, b_dst1, Xs, Xd, ND);
    edge1_kernel<<<GRID_P, 256, 0, stream>>>(
        flag, Xs, Xd, e1_src, e1_dst, e1_cat, e1_cont, emb1,
        gW1, gb1, gW2, gb2, attn1, sb, aggr);
    projout_kernel<<<GRID_P, 256, 0, stream>>>(flag, aggr, sb, Wo_drug, bo_drug, d_out, 0, ND);

    // ---- phase 2: drug -> disease (no gate) ----
    hipMemsetAsync(sb, 0, (size_t)NS * NH * 4, stream);
    hipMemsetAsync(aggr, 0, (size_t)NS * DIM * 4, stream);
    proj1_kernel<<<GRID_P, 256, 0, stream>>>(flag, x_drug, W_src2, b_src2, Xs, ND);
    proj1_kernel<<<GRID_P, 256, 0, stream>>>(flag, x_dis, W_dst2, b_dst2, Xd, NS);
    edge2_kernel<<<NE2, 64, 0, stream>>>(flag, Xs, Xd, e2_src, e2_dst, attn2, sb, aggr);
    projout_kernel<<<GRID_P, 256, 0, stream>>>(flag, aggr, sb, Wo_dis, bo_dis, d_out, (size_t)ND * DIM, NS);
}